// Round 1
// baseline (569.638 us; speedup 1.0000x reference)
//
#include <hip/hip_runtime.h>
#include <math.h>

#define NT 16384   // tokens
#define HD 4096    // hidden dim
#define NE 64      // experts
#define TT 32      // tokens per block (main kernel)
#define DC 64      // d-chunk size
#define NCH (HD / DC)
#define SXS 34     // sX row stride (floats): 136B rows -> float2-aligned, write conflicts <=4-way
#define SLS 65     // score matrix stride (floats): 65 % 32 == 1 -> conflict-free column reads
#define GAP_THRESH 4e-5f   // ~80 sigma of fp32 gap noise (sigma ~ 5e-7)

__device__ __forceinline__ float fsig(float z) { return 1.0f / (1.0f + expf(-z)); }
__device__ __forceinline__ double dsig(double z) { return 1.0 / (1.0 + exp(-z)); }

// Main pass: fp32 GEMM + sigmoid + top-9 bubble. 512 blocks x 256 threads,
// tile 32 tokens x 64 experts, thread tile 2x4. 34 KB LDS -> 2 blocks/CU
// (8 waves/CU). Tokens whose sorted top-9 biased scores have any adjacent
// gap < GAP_THRESH are appended to a flag list for exact fp64 re-resolution.
__global__ __launch_bounds__(256) void moe_gate_f32(
    const float* __restrict__ X, const float* __restrict__ Wg,
    const float* __restrict__ bias, float* __restrict__ out,
    unsigned int* __restrict__ nflag, int* __restrict__ flags) {
  __shared__ float sX[DC][SXS];  // x chunk, transposed [d][token]
  __shared__ float sW[DC][NE];   // W chunk, natural [d][expert] (stride 64: b128 r/w conflict-free)
  __shared__ float sL[TT][SLS];  // sigmoid scores [token][expert]
  __shared__ float sB[NE];

  const int tid   = threadIdx.x;
  const int tok0  = blockIdx.x * TT;
  const int tr    = tid >> 4;    // 0..15 -> tokens {2tr, 2tr+1}
  const int tc    = tid & 15;    // experts {4tc..4tc+3}
  const int tok_s = tid >> 3;    // staging token 0..31
  const int dv    = tid & 7;     // staging d-vec 0..7

  if (tid < NE) sB[tid] = bias[tid];

  float acc[2][4];
#pragma unroll
  for (int i = 0; i < 2; ++i)
#pragma unroll
    for (int j = 0; j < 4; ++j) acc[i][j] = 0.0f;

  const float* xrow = X + (size_t)(tok0 + tok_s) * HD + dv * 8;

  // software pipeline: register prefetch of next chunk
  float4 xr[2], wr[4];
#pragma unroll
  for (int s = 0; s < 2; ++s) xr[s] = *(const float4*)(xrow + s * 4);
#pragma unroll
  for (int s = 0; s < 4; ++s)
    wr[s] = *(const float4*)(Wg + (size_t)(tid + 256 * s) * 4);

  for (int k = 0; k < NCH; ++k) {
    __syncthreads();  // previous chunk's LDS readers done
#pragma unroll
    for (int s = 0; s < 2; ++s) {
      const int d = dv * 8 + s * 4;
      sX[d + 0][tok_s] = xr[s].x;  // transpose once per element
      sX[d + 1][tok_s] = xr[s].y;
      sX[d + 2][tok_s] = xr[s].z;
      sX[d + 3][tok_s] = xr[s].w;
    }
#pragma unroll
    for (int s = 0; s < 4; ++s) {
      const int f = (tid + 256 * s) * 4;     // flat idx into 64x64 W chunk
      *(float4*)&sW[f >> 6][f & 63] = wr[s]; // b128 writes, consecutive lanes -> distinct banks
    }
    __syncthreads();
    if (k + 1 < NCH) {  // next chunk's global loads hide under compute
      const float* xp = xrow + (k + 1) * DC;
      const float* wp = Wg + (size_t)(k + 1) * (DC * NE);
#pragma unroll
      for (int s = 0; s < 2; ++s) xr[s] = *(const float4*)(xp + s * 4);
#pragma unroll
      for (int s = 0; s < 4; ++s)
        wr[s] = *(const float4*)(wp + (size_t)(tid + 256 * s) * 4);
    }
#pragma unroll
    for (int dd = 0; dd < DC; ++dd) {
      const float2 xa = *(const float2*)&sX[dd][tr * 2];  // broadcast (4 addrs/wave)
      const float4 wa = *(const float4*)&sW[dd][tc * 4];  // conflict-free
      acc[0][0] += xa.x * wa.x; acc[0][1] += xa.x * wa.y;
      acc[0][2] += xa.x * wa.z; acc[0][3] += xa.x * wa.w;
      acc[1][0] += xa.y * wa.x; acc[1][1] += xa.y * wa.y;
      acc[1][2] += xa.y * wa.z; acc[1][3] += xa.y * wa.w;
    }
  }

  __syncthreads();
#pragma unroll
  for (int i = 0; i < 2; ++i) {
    const int t = tr * 2 + i;
    sL[t][tc * 4 + 0] = fsig(acc[i][0]);
    sL[t][tc * 4 + 1] = fsig(acc[i][1]);
    sL[t][tc * 4 + 2] = fsig(acc[i][2]);
    sL[t][tc * 4 + 3] = fsig(acc[i][3]);
  }
  __syncthreads();

  // one lane per token: branchless bubble-insert top-9 (rank 9 needed for the
  // 8-vs-9 boundary gap). Strict '>' with ascending e == lowest-index tie-break.
  if (tid < TT) {
    const int t = tid;
    float bsc[9]; int bix[9];
#pragma unroll
    for (int r = 0; r < 9; ++r) { bsc[r] = -INFINITY; bix[r] = 0; }
    for (int e = 0; e < NE; ++e) {
      float cb = sL[t][e] + sB[e];
      int   ci = e;
#pragma unroll
      for (int r = 0; r < 9; ++r) {
        const bool sw = cb > bsc[r];
        const float tb = bsc[r]; const int ti = bix[r];
        bsc[r] = sw ? cb : tb;  bix[r] = sw ? ci : ti;
        cb     = sw ? tb : cb;  ci     = sw ? ti : ci;
      }
    }
    float mg = bsc[0] - bsc[1];
#pragma unroll
    for (int r = 1; r < 8; ++r) mg = fminf(mg, bsc[r] - bsc[r + 1]);

    float us[8]; float sum = 1e-20f;
#pragma unroll
    for (int r = 0; r < 8; ++r) { us[r] = sL[t][bix[r]]; sum += us[r]; }
    const float sc = 2.5f / sum;
    const size_t o = (size_t)(tok0 + t) * 8;
    float4 i0 = {(float)bix[0], (float)bix[1], (float)bix[2], (float)bix[3]};
    float4 i1 = {(float)bix[4], (float)bix[5], (float)bix[6], (float)bix[7]};
    *(float4*)(out + o)     = i0;
    *(float4*)(out + o + 4) = i1;
    float* ow = out + (size_t)NT * 8;
    float4 w0 = {us[0] * sc, us[1] * sc, us[2] * sc, us[3] * sc};
    float4 w1 = {us[4] * sc, us[5] * sc, us[6] * sc, us[7] * sc};
    *(float4*)(ow + o)     = w0;
    *(float4*)(ow + o + 4) = w1;

    if (!(mg > GAP_THRESH)) {  // NaN-safe flag
      const unsigned int p = atomicAdd(nflag, 1u);
      if (p < NT) flags[p] = tok0 + t;
    }
  }
}

// Exact fp64 fallback for flagged (near-tie) tokens. One token per block
// iteration; 256 threads = 32 expert-pairs x 8 K-octants; deterministic
// ordered reduction (same numerics class as the previous all-fp64 kernel).
__global__ __launch_bounds__(256) void moe_gate_fix(
    const float* __restrict__ X, const float* __restrict__ Wg,
    const float* __restrict__ bias, float* __restrict__ out,
    const unsigned int* __restrict__ nflag, const int* __restrict__ flags) {
  __shared__ float  sx[HD];      // 16 KB x row
  __shared__ double sP[NE][9];   // partials [expert][octant], padded
  __shared__ double sS[NE];      // fp64 sigmoid scores

  const int tid = threadIdx.x;
  unsigned int n = *nflag;
  if (n > NT) n = NT;

  for (unsigned int w = blockIdx.x; w < n; w += gridDim.x) {
    const int t = flags[w];
    __syncthreads();  // prev iteration's readers done before restaging
    const float4* xv = (const float4*)(X + (size_t)t * HD);
#pragma unroll
    for (int i = 0; i < 4; ++i)
      ((float4*)sx)[tid + 256 * i] = xv[tid + 256 * i];
    __syncthreads();

    const int ep = (tid & 31) * 2;  // experts {ep, ep+1}
    const int q  = tid >> 5;        // K-octant 0..7 (512 d each)
    const float* wp = Wg + (size_t)(q * 512) * NE + ep;
    const float* xp = sx + q * 512;
    double a0 = 0.0, a1 = 0.0, b0 = 0.0, b1 = 0.0;
    for (int d = 0; d < 512; d += 2) {
      const double x0 = (double)xp[d];
      const double x1 = (double)xp[d + 1];
      const float2 w0 = *(const float2*)(wp + (size_t)d * NE);
      const float2 w1 = *(const float2*)(wp + (size_t)(d + 1) * NE);
      a0 += x0 * (double)w0.x; a1 += x0 * (double)w0.y;
      b0 += x1 * (double)w1.x; b1 += x1 * (double)w1.y;
    }
    sP[ep][q]     = a0 + b0;
    sP[ep + 1][q] = a1 + b1;
    __syncthreads();
    if (tid < NE) {
      double s = 0.0;
#pragma unroll
      for (int q8 = 0; q8 < 8; ++q8) s += sP[tid][q8];  // fixed ascending order
      sS[tid] = dsig(s);
    }
    __syncthreads();
    if (tid == 0) {
      double bsc[8]; int bix[8];
#pragma unroll
      for (int r = 0; r < 8; ++r) { bsc[r] = -INFINITY; bix[r] = 0; }
      for (int e = 0; e < NE; ++e) {
        double cb = sS[e] + (double)bias[e];
        int   ci = e;
#pragma unroll
        for (int r = 0; r < 8; ++r) {
          const bool sw = cb > bsc[r];
          const double tb = bsc[r]; const int ti = bix[r];
          bsc[r] = sw ? cb : tb;  bix[r] = sw ? ci : ti;
          cb     = sw ? tb : cb;  ci     = sw ? ti : ci;
        }
      }
      double us[8]; double sum = 1e-20;
#pragma unroll
      for (int r = 0; r < 8; ++r) { us[r] = sS[bix[r]]; sum += us[r]; }
      const double sc = 2.5 / sum;
      const size_t o = (size_t)t * 8;
      float4 i0 = {(float)bix[0], (float)bix[1], (float)bix[2], (float)bix[3]};
      float4 i1 = {(float)bix[4], (float)bix[5], (float)bix[6], (float)bix[7]};
      *(float4*)(out + o)     = i0;
      *(float4*)(out + o + 4) = i1;
      float* ow = out + (size_t)NT * 8;
      float4 w0 = {(float)(us[0] * sc), (float)(us[1] * sc),
                   (float)(us[2] * sc), (float)(us[3] * sc)};
      float4 w1 = {(float)(us[4] * sc), (float)(us[5] * sc),
                   (float)(us[6] * sc), (float)(us[7] * sc)};
      *(float4*)(ow + o)     = w0;
      *(float4*)(ow + o + 4) = w1;
    }
  }
}

extern "C" void kernel_launch(void* const* d_in, const int* in_sizes, int n_in,
                              void* d_out, int out_size, void* d_ws, size_t ws_size,
                              hipStream_t stream) {
  const float* X  = (const float*)d_in[0];
  const float* Wg = (const float*)d_in[1];
  const float* b  = (const float*)d_in[2];
  float* out = (float*)d_out;
  // workspace: [0..4) flag count, [64..64+4*NT) flag token list (~64.1 KB)
  unsigned int* nflag = (unsigned int*)d_ws;
  int* flags = (int*)((char*)d_ws + 64);
  hipMemsetAsync(d_ws, 0, 64, stream);
  hipLaunchKernelGGL(moe_gate_f32, dim3(NT / TT), dim3(256), 0, stream,
                     X, Wg, b, out, nflag, flags);
  hipLaunchKernelGGL(moe_gate_fix, dim3(256), dim3(256), 0, stream,
                     X, Wg, b, out, nflag, flags);
}